// Round 1
// 970.928 us; speedup vs baseline: 1.3907x; 1.3907x over previous
//
#include <hip/hip_runtime.h>

#define B_  8
#define S1_ 2048
#define S2_ 2048
#define H_  1024

typedef unsigned short u16;
typedef __attribute__((ext_vector_type(8))) short short8;   // 8 bf16 (4 VGPRs)
typedef __attribute__((ext_vector_type(4))) float f32x4;

__device__ __forceinline__ float b2f(u16 u) {
  union { unsigned int i; float f; } v; v.i = ((unsigned int)u) << 16; return v.f;
}
__device__ __forceinline__ u16 f2b(float f) {
  union { float f; unsigned int i; } v; v.f = f;
  unsigned int r = v.i + 0x7fffu + ((v.i >> 16) & 1u);   // RNE
  return (u16)(r >> 16);
}

// XOR-swizzled u16 element index into a 128x32 bf16 tile.
// Row byte-stride is 64 B = 4 chunks of 16 B; XOR chunk slot (elem bits 3-4)
// with row bits 1-2 so wave64 ds_read_b128/ds_write_b128 spread across all
// 8 bank-groups (8 lanes/group = conflict-free minimum).
__device__ __forceinline__ int swz(int row, int kk) {
  return (row * 32 + kk) ^ (((row >> 1) & 3) << 3);
}

// split fp32 x -> hi(bf16) + lo(bf16), x ~= hi + lo to ~2^-17 rel
__device__ __forceinline__ void cvt8_split(float4 va, float4 vb, short8* hi, short8* lo) {
  float x[8] = {va.x, va.y, va.z, va.w, vb.x, vb.y, vb.z, vb.w};
  short8 h, l;
#pragma unroll
  for (int e = 0; e < 8; ++e) {
    u16 hb = f2b(x[e]);
    h[e] = (short)hb;
    l[e] = (short)f2b(x[e] - b2f(hb));   // residual; subtraction exact (Sterbenz)
  }
  *hi = h; *lo = l;
}
__device__ __forceinline__ short8 cvt8(float4 va, float4 vb) {
  float x[8] = {va.x, va.y, va.z, va.w, vb.x, vb.y, vb.z, vb.w};
  short8 h;
#pragma unroll
  for (int e = 0; e < 8; ++e) h[e] = (short)f2b(x[e]);
  return h;
}

// C[m,n] = sum_k A[m,k] * B'[k,n], all fp32 in HBM, bf16 MFMA internally.
// BTR=0: B is [N,K] row-major (ldb=K).  BTR=1: B is [K,N] row-major (ldb=N);
//        staged k-major per thread (coalesced scalar loads, vector LDS stores).
// SPLIT=1: 3-pass hi/lo bf16 (~fp32-accurate).  DO_MASK: mask[b,n,m]!=0 -> C=-1e30. ADD_BIAS: +bias[n].
template<bool ADD_BIAS, bool DO_MASK, bool SPLIT, bool BTR>
__global__ __launch_bounds__(256)
void gemm_k(const float* __restrict__ A, long sA,
            const float* __restrict__ B, long sB, int ldb,
            const float* __restrict__ bias,
            const int* __restrict__ mask, long sMask, int mask_ld,
            float* __restrict__ C, long sC, int ldc, int K)
{
  // tile[0]=A hi, tile[1]=B hi, tile[2]=A lo, tile[3]=B lo (lo only when SPLIT)
  __shared__ __align__(16) union {
    u16 tile[SPLIT ? 4 : 2][128 * 32];                       // 32 KB / 16 KB
    unsigned char m[128][128];                               // mask tile (epilogue)
  } sh;

  const int t    = threadIdx.x;
  const int lane = t & 63;
  const int wv   = t >> 6;
  const int wm   = wv >> 1, wn = wv & 1;
  const int batch = blockIdx.z;
  const int m0 = blockIdx.x * 128;
  const int n0 = blockIdx.y * 128;

  const float* Ab = A + (long)batch * sA + (long)m0 * K;
  const float* Bb = B + (long)batch * sB + (BTR ? (long)n0 : (long)n0 * ldb);

  f32x4 acc[4][4];
#pragma unroll
  for (int i = 0; i < 4; ++i)
#pragma unroll
    for (int j = 0; j < 4; ++j)
      acc[i][j] = (f32x4){0.f, 0.f, 0.f, 0.f};

  // A-tile chunks: 8 consecutive k per chunk; c=t covers rows 0..63, c=t+256 rows 64..127
  const int c0 = t,       r0 = c0 >> 2, o0 = (c0 & 3) * 8;
  const int c1 = t + 256, r1 = c1 >> 2, o1 = (c1 & 3) * 8;

  const int fr = lane & 15;     // fragment row (m or n within 16)
  const int kg = lane >> 4;     // k-group 0..3 (8 bf16 each)

  for (int kc = 0; kc < K; kc += 32) {
    // ---- global loads (fp32), hoisted above barrier ----
    float4 a00 = *(const float4*)(Ab + (long)r0 * K + kc + o0);
    float4 a01 = *(const float4*)(Ab + (long)r0 * K + kc + o0 + 4);
    float4 a10 = *(const float4*)(Ab + (long)r1 * K + kc + o1);
    float4 a11 = *(const float4*)(Ab + (long)r1 * K + kc + o1 + 4);
    float4 bb[4];
    float btv[2][8];
    if (BTR) {
      // k-major per thread: thread owns cols n = lane, lane+64 and k-octet wv.
      // Per instruction (fixed p,e): 64 lanes read 64 consecutive floats -> coalesced.
#pragma unroll
      for (int p = 0; p < 2; ++p)
#pragma unroll
        for (int e = 0; e < 8; ++e)
          btv[p][e] = Bb[(long)(kc + wv * 8 + e) * ldb + lane + p * 64];
    } else {
      bb[0] = *(const float4*)(Bb + (long)r0 * ldb + kc + o0);
      bb[1] = *(const float4*)(Bb + (long)r0 * ldb + kc + o0 + 4);
      bb[2] = *(const float4*)(Bb + (long)r1 * ldb + kc + o1);
      bb[3] = *(const float4*)(Bb + (long)r1 * ldb + kc + o1 + 4);
    }
    __syncthreads();   // prior iteration's ds_reads retired before overwrite

    if (SPLIT) {
      short8 h, l;
      cvt8_split(a00, a01, &h, &l);
      *(short8*)&sh.tile[0][swz(r0, o0)] = h;  *(short8*)&sh.tile[2][swz(r0, o0)] = l;
      cvt8_split(a10, a11, &h, &l);
      *(short8*)&sh.tile[0][swz(r1, o1)] = h;  *(short8*)&sh.tile[2][swz(r1, o1)] = l;
      cvt8_split(bb[0], bb[1], &h, &l);
      *(short8*)&sh.tile[1][swz(r0, o0)] = h;  *(short8*)&sh.tile[3][swz(r0, o0)] = l;
      cvt8_split(bb[2], bb[3], &h, &l);
      *(short8*)&sh.tile[1][swz(r1, o1)] = h;  *(short8*)&sh.tile[3][swz(r1, o1)] = l;
    } else {
      *(short8*)&sh.tile[0][swz(r0, o0)] = cvt8(a00, a01);
      *(short8*)&sh.tile[0][swz(r1, o1)] = cvt8(a10, a11);
      if (BTR) {
#pragma unroll
        for (int p = 0; p < 2; ++p) {
          short8 h;
#pragma unroll
          for (int e = 0; e < 8; ++e) h[e] = (short)f2b(btv[p][e]);
          *(short8*)&sh.tile[1][swz(lane + p * 64, wv * 8)] = h;   // [n][k], vector store
        }
      } else {
        *(short8*)&sh.tile[1][swz(r0, o0)] = cvt8(bb[0], bb[1]);
        *(short8*)&sh.tile[1][swz(r1, o1)] = cvt8(bb[2], bb[3]);
      }
    }
    __syncthreads();

    short8 afh[4], bfh[4];
#pragma unroll
    for (int i = 0; i < 4; ++i)
      afh[i] = *(const short8*)&sh.tile[0][swz(wm * 64 + i * 16 + fr, kg * 8)];
#pragma unroll
    for (int j = 0; j < 4; ++j)
      bfh[j] = *(const short8*)&sh.tile[1][swz(wn * 64 + j * 16 + fr, kg * 8)];

    if (SPLIT) {
      short8 afl[4], bfl[4];
#pragma unroll
      for (int i = 0; i < 4; ++i)
        afl[i] = *(const short8*)&sh.tile[2][swz(wm * 64 + i * 16 + fr, kg * 8)];
#pragma unroll
      for (int j = 0; j < 4; ++j)
        bfl[j] = *(const short8*)&sh.tile[3][swz(wn * 64 + j * 16 + fr, kg * 8)];
#pragma unroll
      for (int i = 0; i < 4; ++i)
#pragma unroll
        for (int j = 0; j < 4; ++j) {
          acc[i][j] = __builtin_amdgcn_mfma_f32_16x16x32_bf16(afh[i], bfh[j], acc[i][j], 0, 0, 0);
          acc[i][j] = __builtin_amdgcn_mfma_f32_16x16x32_bf16(afh[i], bfl[j], acc[i][j], 0, 0, 0);
          acc[i][j] = __builtin_amdgcn_mfma_f32_16x16x32_bf16(afl[i], bfh[j], acc[i][j], 0, 0, 0);
        }
    } else {
#pragma unroll
      for (int i = 0; i < 4; ++i)
#pragma unroll
        for (int j = 0; j < 4; ++j)
          acc[i][j] = __builtin_amdgcn_mfma_f32_16x16x32_bf16(afh[i], bfh[j], acc[i][j], 0, 0, 0);
    }
  }

  if (DO_MASK) {
    __syncthreads();  // retire last fragment ds_reads before LDS reuse as mask tile
    const int* mb = mask + (long)batch * sMask;
#pragma unroll
    for (int it = 0; it < 16; ++it) {
      int ql = it * 8 + (t >> 5);       // q (col of C): mask row -> coalesced int4 reads
      int kl = (t & 31) * 4;            // k (row of C)
      int4 mv = *(const int4*)(mb + (long)(n0 + ql) * mask_ld + (m0 + kl));
      sh.m[kl + 0][ql] = (unsigned char)(mv.x != 0);
      sh.m[kl + 1][ql] = (unsigned char)(mv.y != 0);
      sh.m[kl + 2][ql] = (unsigned char)(mv.z != 0);
      sh.m[kl + 3][ql] = (unsigned char)(mv.w != 0);
    }
    __syncthreads();
  }

  float bv[4];
  if (ADD_BIAS) {
#pragma unroll
    for (int j = 0; j < 4; ++j)
      bv[j] = bias[n0 + wn * 64 + j * 16 + fr];
  }

#pragma unroll
  for (int i = 0; i < 4; ++i) {
#pragma unroll
    for (int r = 0; r < 4; ++r) {
      int row = wm * 64 + i * 16 + (lane >> 4) * 4 + r;   // C row = m  [m89/m91 layout]
      long gro = (long)batch * sC + (long)(m0 + row) * ldc + n0;
#pragma unroll
      for (int j = 0; j < 4; ++j) {
        int col = wn * 64 + j * 16 + fr;                  // C col = n
        float v = acc[i][j][r];
        if (ADD_BIAS) v += bv[j];
        if (DO_MASK && sh.m[row][col]) v = -1e30f;
        C[gro + col] = v;
      }
    }
  }
}

// one block per row: in-place softmax over S1 contiguous fp32
__global__ __launch_bounds__(256)
void softmax_rows(float* __restrict__ scores)
{
  const long row = blockIdx.x;
  float* p = scores + row * (long)S1_;
  const int t = threadIdx.x;
  const int lane = t & 63, wv = t >> 6;

  float4 v0 = *(const float4*)(p + t * 8);
  float4 v1 = *(const float4*)(p + t * 8 + 4);
  float x[8] = {v0.x, v0.y, v0.z, v0.w, v1.x, v1.y, v1.z, v1.w};

  float m = x[0];
#pragma unroll
  for (int q = 1; q < 8; ++q) m = fmaxf(m, x[q]);
#pragma unroll
  for (int o = 32; o; o >>= 1) m = fmaxf(m, __shfl_xor(m, o));
  __shared__ float rb[4], sb[4];
  if (lane == 0) rb[wv] = m;
  __syncthreads();
  m = fmaxf(fmaxf(rb[0], rb[1]), fmaxf(rb[2], rb[3]));

  float e[8]; float s = 0.f;
#pragma unroll
  for (int q = 0; q < 8; ++q) { e[q] = __expf(x[q] - m); s += e[q]; }
#pragma unroll
  for (int o = 32; o; o >>= 1) s += __shfl_xor(s, o);
  if (lane == 0) sb[wv] = s;
  __syncthreads();
  s = sb[0] + sb[1] + sb[2] + sb[3];
  float inv = 1.f / s;

  float4 w0, w1;
  w0.x = e[0] * inv; w0.y = e[1] * inv; w0.z = e[2] * inv; w0.w = e[3] * inv;
  w1.x = e[4] * inv; w1.y = e[5] * inv; w1.z = e[6] * inv; w1.w = e[7] * inv;
  *(float4*)(p + t * 8)     = w0;
  *(float4*)(p + t * 8 + 4) = w1;
}

extern "C" void kernel_launch(void* const* d_in, const int* in_sizes, int n_in,
                              void* d_out, int out_size, void* d_ws, size_t ws_size,
                              hipStream_t stream)
{
  const float* value = (const float*)d_in[0];
  const float* key   = (const float*)d_in[1];
  const float* query = (const float*)d_in[2];
  const int*   mask  = (const int*)d_in[3];
  const float* W     = (const float*)d_in[4];
  const float* bias  = (const float*)d_in[5];

  float* ctx = (float*)d_out;                       // [B,S2,H] fp32; holds q_proj until K5
  float* wts = ctx + (size_t)B_ * S2_ * H_;         // [B,S2,S1] fp32; holds scores pre-softmax
  float* qproj = ctx;                               // [B,S1,H] fp32 == ctx region exactly

  dim3 blk(256);

  // K1: q_proj = query @ W^T + b  (split-bf16 3-pass; M = B*S1 flattened) -> ctx region
  gemm_k<true, false, true, false><<<dim3((B_ * S1_) / 128, H_ / 128, 1), blk, 0, stream>>>(
      query, 0, W, 0, H_, bias, nullptr, 0, 0, qproj, 0, H_, H_);

  // K2: scores[b,s2,s1] = key[b] @ q_proj[b]^T, mask[b,s1,s2]!=0 -> -1e30  (split 3-pass)
  gemm_k<false, true, true, false><<<dim3(S2_ / 128, S1_ / 128, B_), blk, 0, stream>>>(
      key, (long)S2_ * H_, qproj, (long)S1_ * H_, H_, nullptr,
      mask, (long)S1_ * S2_, S2_, wts, (long)S2_ * S1_, S1_, H_);

  // K3: in-place row softmax over S1
  softmax_rows<<<dim3(B_ * S2_), blk, 0, stream>>>(wts);

  // K5: context[b,s2,h] = weights[b] @ value[b]  (plain bf16; B staged k-major, no transpose conflicts)
  gemm_k<false, false, false, true><<<dim3(S2_ / 128, H_ / 128, B_), blk, 0, stream>>>(
      wts, (long)S2_ * S1_, value, (long)S1_ * H_, H_, nullptr,
      nullptr, 0, 0, ctx, (long)S2_ * H_, H_, S1_);
}

// Round 3
// 950.410 us; speedup vs baseline: 1.4207x; 1.0216x over previous
//
#include <hip/hip_runtime.h>

#define B_  8
#define S1_ 2048
#define S2_ 2048
#define H_  1024

typedef unsigned short u16;
typedef __attribute__((ext_vector_type(8))) short short8;   // 8 bf16 (4 VGPRs)
typedef __attribute__((ext_vector_type(4))) float f32x4;

__device__ __forceinline__ float b2f(u16 u) {
  union { unsigned int i; float f; } v; v.i = ((unsigned int)u) << 16; return v.f;
}
__device__ __forceinline__ u16 f2b(float f) {
  union { float f; unsigned int i; } v; v.f = f;
  unsigned int r = v.i + 0x7fffu + ((v.i >> 16) & 1u);   // RNE
  return (u16)(r >> 16);
}

// XOR-swizzled u16 element index into a 128x32 bf16 tile (row*32+kk elements).
// XOR chunk slot (elem bits 3-4) with row bits 1-2: wave64 ds_read_b128 fragment
// reads spread across all 8 bank-groups (8 lanes/group = conflict-free minimum).
__device__ __forceinline__ int swz(int row, int kk) {
  return (row * 32 + kk) ^ (((row >> 1) & 3) << 3);
}

// split fp32 x -> hi(bf16) + lo(bf16), x ~= hi + lo to ~2^-17 rel
__device__ __forceinline__ void cvt8_split(float4 va, float4 vb, short8* hi, short8* lo) {
  float x[8] = {va.x, va.y, va.z, va.w, vb.x, vb.y, vb.z, vb.w};
  short8 h, l;
#pragma unroll
  for (int e = 0; e < 8; ++e) {
    u16 hb = f2b(x[e]);
    h[e] = (short)hb;
    l[e] = (short)f2b(x[e] - b2f(hb));   // residual; subtraction exact (Sterbenz)
  }
  *hi = h; *lo = l;
}
__device__ __forceinline__ short8 cvt8(float4 va, float4 vb) {
  float x[8] = {va.x, va.y, va.z, va.w, vb.x, vb.y, vb.z, vb.w};
  short8 h;
#pragma unroll
  for (int e = 0; e < 8; ++e) h[e] = (short)f2b(x[e]);
  return h;
}

// async 16B global->LDS (direct, no VGPR roundtrip). LDS dest must be
// wave-uniform (HW writes base + lane*16); global src is per-lane.
__device__ __forceinline__ void g2l16(const void* g, void* lds) {
  __builtin_amdgcn_global_load_lds(
      (const __attribute__((address_space(1))) unsigned int*)g,
      (__attribute__((address_space(3))) unsigned int*)lds, 16, 0, 0);
}

// ===========================================================================
// PATH A (needs >=132MB workspace): all-bf16 GEMM, global_load_lds staging.
// C[m,n] = sum_k A[m,k]*B[n,k]  (operands [rows][K] row-major bf16)
// SPLIT: A/B have hi+lo planes, 3-pass MFMA (~fp32 accuracy).
// OUTSPLIT: write C as bf16 hi/lo planes.  DO_MASK: mask[b,n,m]!=0 -> -1e30.
// Staging: linear LDS dest + inverse-swizzled global source + swizzled reads.
// ===========================================================================
template<bool ADD_BIAS, bool DO_MASK, bool SPLIT, bool OUTSPLIT>
__global__ __launch_bounds__(256)
void gemm_bf(const u16* __restrict__ Ahi, const u16* __restrict__ Alo, long sA, int lda,
             const u16* __restrict__ Bhi, const u16* __restrict__ Blo, long sB, int ldb,
             const float* __restrict__ bias,
             const int* __restrict__ mask, long sMask, int mask_ld,
             float* __restrict__ Cf, u16* __restrict__ Chi, u16* __restrict__ Clo,
             long sC, int ldc, int K)
{
  __shared__ __align__(16) union {
    u16 tile[SPLIT ? 4 : 2][128 * 32];                       // 32 KB / 16 KB
    unsigned char m[128][128];                               // mask tile (epilogue)
  } sh;

  const int t    = threadIdx.x;
  const int lane = t & 63;
  const int wv   = t >> 6;
  const int wm   = wv >> 1, wn = wv & 1;
  const int batch = blockIdx.z;
  const int m0 = blockIdx.x * 128;
  const int n0 = blockIdx.y * 128;

  const u16* Ah = Ahi + (long)batch * sA + (long)m0 * lda;
  const u16* Bh = Bhi + (long)batch * sB + (long)n0 * ldb;
  const u16* Al = SPLIT ? (Alo + (long)batch * sA + (long)m0 * lda) : nullptr;
  const u16* Bl = SPLIT ? (Blo + (long)batch * sB + (long)n0 * ldb) : nullptr;

  f32x4 acc[4][4];
#pragma unroll
  for (int i = 0; i < 4; ++i)
#pragma unroll
    for (int j = 0; j < 4; ++j)
      acc[i][j] = (f32x4){0.f, 0.f, 0.f, 0.f};

  const int fr = lane & 15;     // fragment row (m or n within 16)
  const int kg = lane >> 4;     // k-group 0..3 (8 bf16 each)

  // chunk c = half*256 + wv*64 + lane; row=c>>2. Global chunk = (c&3)^s(row)
  // so linear LDS slot c holds the swizzled image.
  int srow[2], soff[2], sdst[2];
#pragma unroll
  for (int half = 0; half < 2; ++half) {
    int c = half * 256 + wv * 64 + lane;
    int row = c >> 2;
    srow[half] = row;
    soff[half] = (((c & 3) ^ ((row >> 1) & 3)) * 8);
    sdst[half] = (half * 256 + wv * 64) * 8;     // wave-uniform u16 index
  }

  for (int kc = 0; kc < K; kc += 32) {
    __syncthreads();   // prior iteration's ds_reads retired before overwrite
#pragma unroll
    for (int half = 0; half < 2; ++half) {
      const int ga = srow[half] * lda + kc + soff[half];
      const int gb = srow[half] * ldb + kc + soff[half];
      g2l16(Ah + ga, &sh.tile[0][sdst[half]]);
      g2l16(Bh + gb, &sh.tile[1][sdst[half]]);
      if (SPLIT) {
        g2l16(Al + ga, &sh.tile[2][sdst[half]]);
        g2l16(Bl + gb, &sh.tile[3][sdst[half]]);
      }
    }
    __syncthreads();   // drains vmcnt(0): staged data visible

    short8 afh[4], bfh[4];
#pragma unroll
    for (int i = 0; i < 4; ++i)
      afh[i] = *(const short8*)&sh.tile[0][swz(wm * 64 + i * 16 + fr, kg * 8)];
#pragma unroll
    for (int j = 0; j < 4; ++j)
      bfh[j] = *(const short8*)&sh.tile[1][swz(wn * 64 + j * 16 + fr, kg * 8)];

    if (SPLIT) {
      short8 afl[4], bfl[4];
#pragma unroll
      for (int i = 0; i < 4; ++i)
        afl[i] = *(const short8*)&sh.tile[2][swz(wm * 64 + i * 16 + fr, kg * 8)];
#pragma unroll
      for (int j = 0; j < 4; ++j)
        bfl[j] = *(const short8*)&sh.tile[3][swz(wn * 64 + j * 16 + fr, kg * 8)];
#pragma unroll
      for (int i = 0; i < 4; ++i)
#pragma unroll
        for (int j = 0; j < 4; ++j) {
          acc[i][j] = __builtin_amdgcn_mfma_f32_16x16x32_bf16(afh[i], bfh[j], acc[i][j], 0, 0, 0);
          acc[i][j] = __builtin_amdgcn_mfma_f32_16x16x32_bf16(afh[i], bfl[j], acc[i][j], 0, 0, 0);
          acc[i][j] = __builtin_amdgcn_mfma_f32_16x16x32_bf16(afl[i], bfh[j], acc[i][j], 0, 0, 0);
        }
    } else {
#pragma unroll
      for (int i = 0; i < 4; ++i)
#pragma unroll
        for (int j = 0; j < 4; ++j)
          acc[i][j] = __builtin_amdgcn_mfma_f32_16x16x32_bf16(afh[i], bfh[j], acc[i][j], 0, 0, 0);
    }
  }

  if (DO_MASK) {
    __syncthreads();
    const int* mb = mask + (long)batch * sMask;
#pragma unroll
    for (int it = 0; it < 16; ++it) {
      int ql = it * 8 + (t >> 5);
      int kl = (t & 31) * 4;
      int4 mv = *(const int4*)(mb + (long)(n0 + ql) * mask_ld + (m0 + kl));
      sh.m[kl + 0][ql] = (unsigned char)(mv.x != 0);
      sh.m[kl + 1][ql] = (unsigned char)(mv.y != 0);
      sh.m[kl + 2][ql] = (unsigned char)(mv.z != 0);
      sh.m[kl + 3][ql] = (unsigned char)(mv.w != 0);
    }
    __syncthreads();
  }

  float bv[4];
  if (ADD_BIAS) {
#pragma unroll
    for (int j = 0; j < 4; ++j)
      bv[j] = bias[n0 + wn * 64 + j * 16 + fr];
  }

#pragma unroll
  for (int i = 0; i < 4; ++i) {
#pragma unroll
    for (int r = 0; r < 4; ++r) {
      int row = wm * 64 + i * 16 + (lane >> 4) * 4 + r;   // C row = m  [m89/m91]
      long gro = (long)batch * sC + (long)(m0 + row) * ldc + n0;
#pragma unroll
      for (int j = 0; j < 4; ++j) {
        int col = wn * 64 + j * 16 + fr;                  // C col = n
        float v = acc[i][j][r];
        if (ADD_BIAS) v += bv[j];
        if (OUTSPLIT) {
          u16 hb = f2b(v);
          Chi[gro + col] = hb;
          Clo[gro + col] = f2b(v - b2f(hb));
        } else {
          if (DO_MASK && sh.m[row][col]) v = -1e30f;
          Cf[gro + col] = v;
        }
      }
    }
  }
}

// ===========================================================================
// PATH B (fallback, zero workspace): fp32-input GEMM with per-tile conversion.
// Verified at 971us. BTR=1: B is [K,N], staged k-major per thread.
// ===========================================================================
template<bool ADD_BIAS, bool DO_MASK, bool SPLIT, bool BTR>
__global__ __launch_bounds__(256)
void gemm_k(const float* __restrict__ A, long sA,
            const float* __restrict__ B, long sB, int ldb,
            const float* __restrict__ bias,
            const int* __restrict__ mask, long sMask, int mask_ld,
            float* __restrict__ C, long sC, int ldc, int K)
{
  __shared__ __align__(16) union {
    u16 tile[SPLIT ? 4 : 2][128 * 32];
    unsigned char m[128][128];
  } sh;

  const int t    = threadIdx.x;
  const int lane = t & 63;
  const int wv   = t >> 6;
  const int wm   = wv >> 1, wn = wv & 1;
  const int batch = blockIdx.z;
  const int m0 = blockIdx.x * 128;
  const int n0 = blockIdx.y * 128;

  const float* Ab = A + (long)batch * sA + (long)m0 * K;
  const float* Bb = B + (long)batch * sB + (BTR ? (long)n0 : (long)n0 * ldb);

  f32x4 acc[4][4];
#pragma unroll
  for (int i = 0; i < 4; ++i)
#pragma unroll
    for (int j = 0; j < 4; ++j)
      acc[i][j] = (f32x4){0.f, 0.f, 0.f, 0.f};

  const int c0 = t,       r0 = c0 >> 2, o0 = (c0 & 3) * 8;
  const int c1 = t + 256, r1 = c1 >> 2, o1 = (c1 & 3) * 8;

  const int fr = lane & 15;
  const int kg = lane >> 4;

  for (int kc = 0; kc < K; kc += 32) {
    float4 a00 = *(const float4*)(Ab + (long)r0 * K + kc + o0);
    float4 a01 = *(const float4*)(Ab + (long)r0 * K + kc + o0 + 4);
    float4 a10 = *(const float4*)(Ab + (long)r1 * K + kc + o1);
    float4 a11 = *(const float4*)(Ab + (long)r1 * K + kc + o1 + 4);
    float4 bb[4];
    float btv[2][8];
    if (BTR) {
#pragma unroll
      for (int p = 0; p < 2; ++p)
#pragma unroll
        for (int e = 0; e < 8; ++e)
          btv[p][e] = Bb[(long)(kc + wv * 8 + e) * ldb + lane + p * 64];
    } else {
      bb[0] = *(const float4*)(Bb + (long)r0 * ldb + kc + o0);
      bb[1] = *(const float4*)(Bb + (long)r0 * ldb + kc + o0 + 4);
      bb[2] = *(const float4*)(Bb + (long)r1 * ldb + kc + o1);
      bb[3] = *(const float4*)(Bb + (long)r1 * ldb + kc + o1 + 4);
    }
    __syncthreads();

    if (SPLIT) {
      short8 h, l;
      cvt8_split(a00, a01, &h, &l);
      *(short8*)&sh.tile[0][swz(r0, o0)] = h;  *(short8*)&sh.tile[2][swz(r0, o0)] = l;
      cvt8_split(a10, a11, &h, &l);
      *(short8*)&sh.tile[0][swz(r1, o1)] = h;  *(short8*)&sh.tile[2][swz(r1, o1)] = l;
      cvt8_split(bb[0], bb[1], &h, &l);
      *(short8*)&sh.tile[1][swz(r0, o0)] = h;  *(short8*)&sh.tile[3][swz(r0, o0)] = l;
      cvt8_split(bb[2], bb[3], &h, &l);
      *(short8*)&sh.tile[1][swz(r1, o1)] = h;  *(short8*)&sh.tile[3][swz(r1, o1)] = l;
    } else {
      *(short8*)&sh.tile[0][swz(r0, o0)] = cvt8(a00, a01);
      *(short8*)&sh.tile[0][swz(r1, o1)] = cvt8(a10, a11);
      if (BTR) {
#pragma unroll
        for (int p = 0; p < 2; ++p) {
          short8 h;
#pragma unroll
          for (int e = 0; e < 8; ++e) h[e] = (short)f2b(btv[p][e]);
          *(short8*)&sh.tile[1][swz(lane + p * 64, wv * 8)] = h;
        }
      } else {
        *(short8*)&sh.tile[1][swz(r0, o0)] = cvt8(bb[0], bb[1]);
        *(short8*)&sh.tile[1][swz(r1, o1)] = cvt8(bb[2], bb[3]);
      }
    }
    __syncthreads();

    short8 afh[4], bfh[4];
#pragma unroll
    for (int i = 0; i < 4; ++i)
      afh[i] = *(const short8*)&sh.tile[0][swz(wm * 64 + i * 16 + fr, kg * 8)];
#pragma unroll
    for (int j = 0; j < 4; ++j)
      bfh[j] = *(const short8*)&sh.tile[1][swz(wn * 64 + j * 16 + fr, kg * 8)];

    if (SPLIT) {
      short8 afl[4], bfl[4];
#pragma unroll
      for (int i = 0; i < 4; ++i)
        afl[i] = *(const short8*)&sh.tile[2][swz(wm * 64 + i * 16 + fr, kg * 8)];
#pragma unroll
      for (int j = 0; j < 4; ++j)
        bfl[j] = *(const short8*)&sh.tile[3][swz(wn * 64 + j * 16 + fr, kg * 8)];
#pragma unroll
      for (int i = 0; i < 4; ++i)
#pragma unroll
        for (int j = 0; j < 4; ++j) {
          acc[i][j] = __builtin_amdgcn_mfma_f32_16x16x32_bf16(afh[i], bfh[j], acc[i][j], 0, 0, 0);
          acc[i][j] = __builtin_amdgcn_mfma_f32_16x16x32_bf16(afh[i], bfl[j], acc[i][j], 0, 0, 0);
          acc[i][j] = __builtin_amdgcn_mfma_f32_16x16x32_bf16(afl[i], bfh[j], acc[i][j], 0, 0, 0);
        }
    } else {
#pragma unroll
      for (int i = 0; i < 4; ++i)
#pragma unroll
        for (int j = 0; j < 4; ++j)
          acc[i][j] = __builtin_amdgcn_mfma_f32_16x16x32_bf16(afh[i], bfh[j], acc[i][j], 0, 0, 0);
    }
  }

  if (DO_MASK) {
    __syncthreads();
    const int* mb = mask + (long)batch * sMask;
#pragma unroll
    for (int it = 0; it < 16; ++it) {
      int ql = it * 8 + (t >> 5);
      int kl = (t & 31) * 4;
      int4 mv = *(const int4*)(mb + (long)(n0 + ql) * mask_ld + (m0 + kl));
      sh.m[kl + 0][ql] = (unsigned char)(mv.x != 0);
      sh.m[kl + 1][ql] = (unsigned char)(mv.y != 0);
      sh.m[kl + 2][ql] = (unsigned char)(mv.z != 0);
      sh.m[kl + 3][ql] = (unsigned char)(mv.w != 0);
    }
    __syncthreads();
  }

  float bv[4];
  if (ADD_BIAS) {
#pragma unroll
    for (int j = 0; j < 4; ++j)
      bv[j] = bias[n0 + wn * 64 + j * 16 + fr];
  }

#pragma unroll
  for (int i = 0; i < 4; ++i) {
#pragma unroll
    for (int r = 0; r < 4; ++r) {
      int row = wm * 64 + i * 16 + (lane >> 4) * 4 + r;
      long gro = (long)batch * sC + (long)(m0 + row) * ldc + n0;
#pragma unroll
      for (int j = 0; j < 4; ++j) {
        int col = wn * 64 + j * 16 + fr;
        float v = acc[i][j][r];
        if (ADD_BIAS) v += bv[j];
        if (DO_MASK && sh.m[row][col]) v = -1e30f;
        C[gro + col] = v;
      }
    }
  }
}

// elementwise fp32 -> bf16 hi/lo split (len multiple of 2048)
__global__ __launch_bounds__(256)
void conv_split(const float* __restrict__ in, u16* __restrict__ hi, u16* __restrict__ lo)
{
  long i = ((long)blockIdx.x * 256 + threadIdx.x) * 8;
  float4 v0 = *(const float4*)(in + i);
  float4 v1 = *(const float4*)(in + i + 4);
  short8 h, l;
  cvt8_split(v0, v1, &h, &l);
  *(short8*)(hi + i) = h;
  *(short8*)(lo + i) = l;
}

// value [B][S1][H] fp32 -> vT [B][H][S1] bf16, 64x64 LDS tiles
__global__ __launch_bounds__(256)
void transpose_conv(const float* __restrict__ v, u16* __restrict__ vt)
{
  __shared__ u16 tl[64][66];
  const int b  = blockIdx.z;
  const int s0 = blockIdx.x * 64, h0 = blockIdx.y * 64;
  const int tr = threadIdx.x >> 4;
  const int tc = (threadIdx.x & 15) * 4;
  const float* vb = v + ((long)b * S1_ + s0) * H_ + h0;
#pragma unroll
  for (int q = 0; q < 4; ++q) {
    int r = tr + q * 16;
    float4 x = *(const float4*)(vb + (long)r * H_ + tc);
    tl[r][tc + 0] = f2b(x.x); tl[r][tc + 1] = f2b(x.y);
    tl[r][tc + 2] = f2b(x.z); tl[r][tc + 3] = f2b(x.w);
  }
  __syncthreads();
  u16* ob = vt + ((long)b * H_ + h0) * S1_ + s0;
#pragma unroll
  for (int q = 0; q < 4; ++q) {
    int hr = tr + q * 16;
    unsigned int w0 = (unsigned int)tl[tc + 0][hr] | ((unsigned int)tl[tc + 1][hr] << 16);
    unsigned int w1 = (unsigned int)tl[tc + 2][hr] | ((unsigned int)tl[tc + 3][hr] << 16);
    uint2 w = {w0, w1};
    *(uint2*)(ob + (long)hr * S1_ + tc) = w;
  }
}

// one block per row: in-place fp32 softmax over S1; optional bf16 copy
__global__ __launch_bounds__(256)
void softmax_rows(float* __restrict__ scores, u16* __restrict__ wbf)
{
  const long row = blockIdx.x;
  float* p = scores + row * (long)S1_;
  const int t = threadIdx.x;
  const int lane = t & 63, wv = t >> 6;

  float4 v0 = *(const float4*)(p + t * 8);
  float4 v1 = *(const float4*)(p + t * 8 + 4);
  float x[8] = {v0.x, v0.y, v0.z, v0.w, v1.x, v1.y, v1.z, v1.w};

  float m = x[0];
#pragma unroll
  for (int q = 1; q < 8; ++q) m = fmaxf(m, x[q]);
#pragma unroll
  for (int o = 32; o; o >>= 1) m = fmaxf(m, __shfl_xor(m, o));
  __shared__ float rb[4], sb[4];
  if (lane == 0) rb[wv] = m;
  __syncthreads();
  m = fmaxf(fmaxf(rb[0], rb[1]), fmaxf(rb[2], rb[3]));

  float e[8]; float s = 0.f;
#pragma unroll
  for (int q = 0; q < 8; ++q) { e[q] = __expf(x[q] - m); s += e[q]; }
#pragma unroll
  for (int o = 32; o; o >>= 1) s += __shfl_xor(s, o);
  if (lane == 0) sb[wv] = s;
  __syncthreads();
  s = sb[0] + sb[1] + sb[2] + sb[3];
  float inv = 1.f / s;

  float w[8];
#pragma unroll
  for (int q = 0; q < 8; ++q) w[q] = e[q] * inv;
  float4 o0 = {w[0], w[1], w[2], w[3]};
  float4 o1 = {w[4], w[5], w[6], w[7]};
  *(float4*)(p + t * 8)     = o0;
  *(float4*)(p + t * 8 + 4) = o1;

  if (wbf != nullptr) {
    short8 hb;
#pragma unroll
    for (int q = 0; q < 8; ++q) hb[q] = (short)f2b(w[q]);
    *(short8*)(wbf + row * (long)S1_ + t * 8) = hb;
  }
}

extern "C" void kernel_launch(void* const* d_in, const int* in_sizes, int n_in,
                              void* d_out, int out_size, void* d_ws, size_t ws_size,
                              hipStream_t stream)
{
  const float* value = (const float*)d_in[0];
  const float* key   = (const float*)d_in[1];
  const float* query = (const float*)d_in[2];
  const int*   mask  = (const int*)d_in[3];
  const float* W     = (const float*)d_in[4];
  const float* bias  = (const float*)d_in[5];

  float* ctx = (float*)d_out;                       // [B,S2,H] fp32 (final context)
  float* wts = ctx + (size_t)B_ * S2_ * H_;         // [B,S2,S1] fp32 (scores -> weights)

  dim3 blk(256);
  const size_t MB = 1024ull * 1024ull;

  if (ws_size >= 132 * MB && d_ws != nullptr) {
    // ---------------- PATH A: pre-converted bf16 operands ----------------
    // ctx region (64MB) holds q_proj bf16 hi/lo until K5 overwrites it
    u16* pjhi = (u16*)ctx;                            // 32MB
    u16* pjlo = (u16*)ctx + (size_t)B_ * S1_ * H_;    // 32MB

    // ws map: [0,64) khi/klo -> wbf after K2; [64,128) qhi/qlo -> vT after K1;
    //         [128,132) whi/wlo
    char* ws = (char*)d_ws;
    u16* khi = (u16*)(ws);
    u16* klo = (u16*)(ws + 32 * MB);
    u16* wbf = (u16*)(ws);                 // 64MB, after K2
    u16* qhi = (u16*)(ws + 64 * MB);
    u16* qlo = (u16*)(ws + 96 * MB);
    u16* vT  = (u16*)(ws + 64 * MB);       // 32MB, after K1
    u16* whi = (u16*)(ws + 128 * MB);
    u16* wlo = (u16*)(ws + 130 * MB);

    conv_split<<<dim3((B_ * S1_ * H_) / 2048), blk, 0, stream>>>(query, qhi, qlo);
    conv_split<<<dim3((B_ * S2_ * H_) / 2048), blk, 0, stream>>>(key, khi, klo);
    conv_split<<<dim3((H_ * H_) / 2048), blk, 0, stream>>>(W, whi, wlo);

    // K1: q_proj = query @ W^T + b -> bf16 hi/lo planes in ctx region
    gemm_bf<true, false, true, true><<<dim3((B_ * S1_) / 128, H_ / 128, 1), blk, 0, stream>>>(
        qhi, qlo, 0, H_, whi, wlo, 0, H_, bias,
        nullptr, 0, 0, nullptr, pjhi, pjlo, 0, H_, H_);

    // P1: value -> vT bf16 (into dead qhi/qlo region; after K1 in stream order)
    transpose_conv<<<dim3(S1_ / 64, H_ / 64, B_), blk, 0, stream>>>(value, vT);

    // K2: scores[b,s2,s1] = key @ q_proj^T, masked -> fp32 in wts
    gemm_bf<false, true, true, false><<<dim3(S2_ / 128, S1_ / 128, B_), blk, 0, stream>>>(
        khi, klo, (long)S2_ * H_, H_, pjhi, pjlo, (long)S1_ * H_, H_, nullptr,
        mask, (long)S1_ * S2_, S2_, wts, nullptr, nullptr, (long)S2_ * S1_, S1_, H_);

    // K3: softmax in-place + bf16 copy into dead khi/klo region
    softmax_rows<<<dim3(B_ * S2_), blk, 0, stream>>>(wts, wbf);

    // K5: context = weights_bf16 @ value^T_bf16
    gemm_bf<false, false, false, false><<<dim3(S2_ / 128, H_ / 128, B_), blk, 0, stream>>>(
        wbf, nullptr, (long)S2_ * S1_, S1_, vT, nullptr, (long)H_ * S1_, S1_, nullptr,
        nullptr, 0, 0, ctx, nullptr, nullptr, (long)S2_ * H_, H_, S1_);
  } else {
    // ---------------- PATH B: zero-workspace fallback (971us, verified) ----
    float* qproj = ctx;   // [B,S1,H] fp32 == ctx region exactly

    gemm_k<true, false, true, false><<<dim3((B_ * S1_) / 128, H_ / 128, 1), blk, 0, stream>>>(
        query, 0, W, 0, H_, bias, nullptr, 0, 0, qproj, 0, H_, H_);

    gemm_k<false, true, true, false><<<dim3(S2_ / 128, S1_ / 128, B_), blk, 0, stream>>>(
        key, (long)S2_ * H_, qproj, (long)S1_ * H_, H_, nullptr,
        mask, (long)S1_ * S2_, S2_, wts, (long)S2_ * S1_, S1_, H_);

    softmax_rows<<<dim3(B_ * S2_), blk, 0, stream>>>(wts, nullptr);

    gemm_k<false, false, false, true><<<dim3(S2_ / 128, H_ / 128, B_), blk, 0, stream>>>(
        wts, (long)S2_ * S1_, value, (long)S1_ * H_, H_, nullptr,
        nullptr, 0, 0, ctx, (long)S2_ * H_, H_, S1_);
  }
}

// Round 4
// 878.111 us; speedup vs baseline: 1.5377x; 1.0823x over previous
//
#include <hip/hip_runtime.h>

#define B_  8
#define S1_ 2048
#define S2_ 2048
#define H_  1024

typedef unsigned short u16;
typedef __attribute__((ext_vector_type(8))) short short8;   // 8 bf16 (4 VGPRs)
typedef __attribute__((ext_vector_type(4))) float f32x4;

__device__ __forceinline__ float b2f(u16 u) {
  union { unsigned int i; float f; } v; v.i = ((unsigned int)u) << 16; return v.f;
}
__device__ __forceinline__ u16 f2b(float f) {
  union { float f; unsigned int i; } v; v.f = f;
  unsigned int r = v.i + 0x7fffu + ((v.i >> 16) & 1u);   // RNE
  return (u16)(r >> 16);
}

// XOR-swizzled u16 element index into a 128x32 bf16 tile (row*32+kk elements).
// XOR chunk slot (elem bits 3-4) with row bits 1-2: wave64 ds_read_b128 fragment
// reads spread across all 8 bank-groups (8 lanes/group = conflict-free minimum).
__device__ __forceinline__ int swz(int row, int kk) {
  return (row * 32 + kk) ^ (((row >> 1) & 3) << 3);
}

// split fp32 x -> hi(bf16) + lo(bf16), x ~= hi + lo to ~2^-17 rel
__device__ __forceinline__ void cvt8_split(float4 va, float4 vb, short8* hi, short8* lo) {
  float x[8] = {va.x, va.y, va.z, va.w, vb.x, vb.y, vb.z, vb.w};
  short8 h, l;
#pragma unroll
  for (int e = 0; e < 8; ++e) {
    u16 hb = f2b(x[e]);
    h[e] = (short)hb;
    l[e] = (short)f2b(x[e] - b2f(hb));   // residual; subtraction exact (Sterbenz)
  }
  *hi = h; *lo = l;
}
__device__ __forceinline__ short8 cvt8(float4 va, float4 vb) {
  float x[8] = {va.x, va.y, va.z, va.w, vb.x, vb.y, vb.z, vb.w};
  short8 h;
#pragma unroll
  for (int e = 0; e < 8; ++e) h[e] = (short)f2b(x[e]);
  return h;
}

// async 16B global->LDS (direct, no VGPR roundtrip). LDS dest must be
// wave-uniform (HW writes base + lane*16); global src is per-lane.
__device__ __forceinline__ void g2l16(const void* g, void* lds) {
  __builtin_amdgcn_global_load_lds(
      (const __attribute__((address_space(1))) unsigned int*)g,
      (__attribute__((address_space(3))) unsigned int*)lds, 16, 0, 0);
}

// ===========================================================================
// PATH A: all-bf16 GEMM, double-buffered global_load_lds staging (T3-minimum:
// issue next tile's loads BEFORE compute, one barrier/iter so the implicit
// vmcnt(0) drain overlaps ds_read+MFMA of the current tile).
// C[m,n] = sum_k A[m,k]*B[n,k]  (operands [rows][K] row-major bf16)
// SPLIT: A/B have hi+lo planes, 3-pass MFMA (~fp32 accuracy).
// OUTSPLIT: write C as bf16 hi/lo planes.  DO_MASK: mask[b,n,m]!=0 -> -1e30.
// T1 XCD chunk swizzle on the linear block id (all grids are %8 == 0).
// ===========================================================================
template<bool ADD_BIAS, bool DO_MASK, bool SPLIT, bool OUTSPLIT>
__global__ __launch_bounds__(256)
void gemm_bf(const u16* __restrict__ Ahi, const u16* __restrict__ Alo, long sA, int lda,
             const u16* __restrict__ Bhi, const u16* __restrict__ Blo, long sB, int ldb,
             const float* __restrict__ bias,
             const int* __restrict__ mask, long sMask, int mask_ld,
             float* __restrict__ Cf, u16* __restrict__ Chi, u16* __restrict__ Clo,
             long sC, int ldc, int K)
{
  constexpr int NP = SPLIT ? 4 : 2;   // planes: A hi, B hi, [A lo, B lo]
  __shared__ __align__(16) union {
    u16 tile[2][NP][128 * 32];                               // 64 KB / 32 KB
    unsigned char m[128][128];                               // mask tile (epilogue)
  } sh;

  const int t    = threadIdx.x;
  const int lane = t & 63;
  const int wv   = t >> 6;
  const int wm   = wv >> 1, wn = wv & 1;

  // T1: XCD-aware chunked remap (bijective: nwg % 8 == 0 for all call sites).
  const int nbx = gridDim.x, nby = gridDim.y;
  const int id  = blockIdx.x + nbx * (blockIdx.y + nby * blockIdx.z);
  const int cpx = (nbx * nby * (int)gridDim.z) >> 3;
  const int sid = (id & 7) * cpx + (id >> 3);
  const int bx  = sid % nbx;
  const int rem = sid / nbx;
  const int by  = rem % nby;
  const int batch = rem / nby;
  const int m0 = bx * 128;
  const int n0 = by * 128;

  const u16* Ah = Ahi + (long)batch * sA + (long)m0 * lda;
  const u16* Bh = Bhi + (long)batch * sB + (long)n0 * ldb;
  const u16* Al = SPLIT ? (Alo + (long)batch * sA + (long)m0 * lda) : nullptr;
  const u16* Bl = SPLIT ? (Blo + (long)batch * sB + (long)n0 * ldb) : nullptr;

  f32x4 acc[4][4];
#pragma unroll
  for (int i = 0; i < 4; ++i)
#pragma unroll
    for (int j = 0; j < 4; ++j)
      acc[i][j] = (f32x4){0.f, 0.f, 0.f, 0.f};

  const int fr = lane & 15;     // fragment row (m or n within 16)
  const int kg = lane >> 4;     // k-group 0..3 (8 bf16 each)

  // chunk c = half*256 + wv*64 + lane; row=c>>2. Global chunk = (c&3)^s(row)
  // so linear LDS slot c holds the swizzled image.
  int srow[2], soff[2], sdst[2];
#pragma unroll
  for (int half = 0; half < 2; ++half) {
    int c = half * 256 + wv * 64 + lane;
    int row = c >> 2;
    srow[half] = row;
    soff[half] = (((c & 3) ^ ((row >> 1) & 3)) * 8);
    sdst[half] = (half * 256 + wv * 64) * 8;     // wave-uniform u16 index
  }

  auto STAGE = [&](int kc, int bufi) {
#pragma unroll
    for (int half = 0; half < 2; ++half) {
      const int ga = srow[half] * lda + kc + soff[half];
      const int gb = srow[half] * ldb + kc + soff[half];
      g2l16(Ah + ga, &sh.tile[bufi][0][sdst[half]]);
      g2l16(Bh + gb, &sh.tile[bufi][1][sdst[half]]);
      if (SPLIT) {
        g2l16(Al + ga, &sh.tile[bufi][2][sdst[half]]);
        g2l16(Bl + gb, &sh.tile[bufi][3][sdst[half]]);
      }
    }
  };

  STAGE(0, 0);
  __syncthreads();          // implicit vmcnt(0): tile 0 staged & visible
  int cur = 0;

  for (int kc = 0; kc < K; kc += 32) {
    // Issue NEXT tile's loads first: latency hides under this tile's compute.
    // Dest buf[cur^1] was last read two barriers ago -> safe to overwrite.
    if (kc + 32 < K) STAGE(kc + 32, cur ^ 1);

    short8 afh[4], bfh[4];
#pragma unroll
    for (int i = 0; i < 4; ++i)
      afh[i] = *(const short8*)&sh.tile[cur][0][swz(wm * 64 + i * 16 + fr, kg * 8)];
#pragma unroll
    for (int j = 0; j < 4; ++j)
      bfh[j] = *(const short8*)&sh.tile[cur][1][swz(wn * 64 + j * 16 + fr, kg * 8)];

    if (SPLIT) {
      short8 afl[4], bfl[4];
#pragma unroll
      for (int i = 0; i < 4; ++i)
        afl[i] = *(const short8*)&sh.tile[cur][2][swz(wm * 64 + i * 16 + fr, kg * 8)];
#pragma unroll
      for (int j = 0; j < 4; ++j)
        bfl[j] = *(const short8*)&sh.tile[cur][3][swz(wn * 64 + j * 16 + fr, kg * 8)];
      __builtin_amdgcn_s_setprio(1);
#pragma unroll
      for (int i = 0; i < 4; ++i)
#pragma unroll
        for (int j = 0; j < 4; ++j) {
          acc[i][j] = __builtin_amdgcn_mfma_f32_16x16x32_bf16(afh[i], bfh[j], acc[i][j], 0, 0, 0);
          acc[i][j] = __builtin_amdgcn_mfma_f32_16x16x32_bf16(afh[i], bfl[j], acc[i][j], 0, 0, 0);
          acc[i][j] = __builtin_amdgcn_mfma_f32_16x16x32_bf16(afl[i], bfh[j], acc[i][j], 0, 0, 0);
        }
      __builtin_amdgcn_s_setprio(0);
    } else {
      __builtin_amdgcn_s_setprio(1);
#pragma unroll
      for (int i = 0; i < 4; ++i)
#pragma unroll
        for (int j = 0; j < 4; ++j)
          acc[i][j] = __builtin_amdgcn_mfma_f32_16x16x32_bf16(afh[i], bfh[j], acc[i][j], 0, 0, 0);
      __builtin_amdgcn_s_setprio(0);
    }

    // One barrier/iter: drains this iter's ds_reads of buf[cur] (so next iter
    // may overwrite it) AND the just-issued gloads into buf[cur^1] (vmcnt(0)),
    // which by now overlapped ~16 ds_read_b128 + MFMA cluster.
    __syncthreads();
    cur ^= 1;
  }

  if (DO_MASK) {
    const int* mb = mask + (long)batch * sMask;
#pragma unroll
    for (int it = 0; it < 16; ++it) {
      int ql = it * 8 + (t >> 5);
      int kl = (t & 31) * 4;
      int4 mv = *(const int4*)(mb + (long)(n0 + ql) * mask_ld + (m0 + kl));
      sh.m[kl + 0][ql] = (unsigned char)(mv.x != 0);
      sh.m[kl + 1][ql] = (unsigned char)(mv.y != 0);
      sh.m[kl + 2][ql] = (unsigned char)(mv.z != 0);
      sh.m[kl + 3][ql] = (unsigned char)(mv.w != 0);
    }
    __syncthreads();
  }

  float bv[4];
  if (ADD_BIAS) {
#pragma unroll
    for (int j = 0; j < 4; ++j)
      bv[j] = bias[n0 + wn * 64 + j * 16 + fr];
  }

#pragma unroll
  for (int i = 0; i < 4; ++i) {
#pragma unroll
    for (int r = 0; r < 4; ++r) {
      int row = wm * 64 + i * 16 + (lane >> 4) * 4 + r;   // C row = m  [m89/m91]
      long gro = (long)batch * sC + (long)(m0 + row) * ldc + n0;
#pragma unroll
      for (int j = 0; j < 4; ++j) {
        int col = wn * 64 + j * 16 + fr;                  // C col = n
        float v = acc[i][j][r];
        if (ADD_BIAS) v += bv[j];
        if (OUTSPLIT) {
          u16 hb = f2b(v);
          Chi[gro + col] = hb;
          Clo[gro + col] = f2b(v - b2f(hb));
        } else {
          if (DO_MASK && sh.m[row][col]) v = -1e30f;
          Cf[gro + col] = v;
        }
      }
    }
  }
}

// ===========================================================================
// PATH B (fallback, zero workspace): fp32-input GEMM with per-tile conversion.
// Verified at 971us. BTR=1: B is [K,N], staged k-major per thread.
// ===========================================================================
template<bool ADD_BIAS, bool DO_MASK, bool SPLIT, bool BTR>
__global__ __launch_bounds__(256)
void gemm_k(const float* __restrict__ A, long sA,
            const float* __restrict__ B, long sB, int ldb,
            const float* __restrict__ bias,
            const int* __restrict__ mask, long sMask, int mask_ld,
            float* __restrict__ C, long sC, int ldc, int K)
{
  __shared__ __align__(16) union {
    u16 tile[SPLIT ? 4 : 2][128 * 32];
    unsigned char m[128][128];
  } sh;

  const int t    = threadIdx.x;
  const int lane = t & 63;
  const int wv   = t >> 6;
  const int wm   = wv >> 1, wn = wv & 1;
  const int batch = blockIdx.z;
  const int m0 = blockIdx.x * 128;
  const int n0 = blockIdx.y * 128;

  const float* Ab = A + (long)batch * sA + (long)m0 * K;
  const float* Bb = B + (long)batch * sB + (BTR ? (long)n0 : (long)n0 * ldb);

  f32x4 acc[4][4];
#pragma unroll
  for (int i = 0; i < 4; ++i)
#pragma unroll
    for (int j = 0; j < 4; ++j)
      acc[i][j] = (f32x4){0.f, 0.f, 0.f, 0.f};

  const int c0 = t,       r0 = c0 >> 2, o0 = (c0 & 3) * 8;
  const int c1 = t + 256, r1 = c1 >> 2, o1 = (c1 & 3) * 8;

  const int fr = lane & 15;
  const int kg = lane >> 4;

  for (int kc = 0; kc < K; kc += 32) {
    float4 a00 = *(const float4*)(Ab + (long)r0 * K + kc + o0);
    float4 a01 = *(const float4*)(Ab + (long)r0 * K + kc + o0 + 4);
    float4 a10 = *(const float4*)(Ab + (long)r1 * K + kc + o1);
    float4 a11 = *(const float4*)(Ab + (long)r1 * K + kc + o1 + 4);
    float4 bb[4];
    float btv[2][8];
    if (BTR) {
#pragma unroll
      for (int p = 0; p < 2; ++p)
#pragma unroll
        for (int e = 0; e < 8; ++e)
          btv[p][e] = Bb[(long)(kc + wv * 8 + e) * ldb + lane + p * 64];
    } else {
      bb[0] = *(const float4*)(Bb + (long)r0 * ldb + kc + o0);
      bb[1] = *(const float4*)(Bb + (long)r0 * ldb + kc + o0 + 4);
      bb[2] = *(const float4*)(Bb + (long)r1 * ldb + kc + o1);
      bb[3] = *(const float4*)(Bb + (long)r1 * ldb + kc + o1 + 4);
    }
    __syncthreads();

    if (SPLIT) {
      short8 h, l;
      cvt8_split(a00, a01, &h, &l);
      *(short8*)&sh.tile[0][swz(r0, o0)] = h;  *(short8*)&sh.tile[2][swz(r0, o0)] = l;
      cvt8_split(a10, a11, &h, &l);
      *(short8*)&sh.tile[0][swz(r1, o1)] = h;  *(short8*)&sh.tile[2][swz(r1, o1)] = l;
      cvt8_split(bb[0], bb[1], &h, &l);
      *(short8*)&sh.tile[1][swz(r0, o0)] = h;  *(short8*)&sh.tile[3][swz(r0, o0)] = l;
      cvt8_split(bb[2], bb[3], &h, &l);
      *(short8*)&sh.tile[1][swz(r1, o1)] = h;  *(short8*)&sh.tile[3][swz(r1, o1)] = l;
    } else {
      *(short8*)&sh.tile[0][swz(r0, o0)] = cvt8(a00, a01);
      *(short8*)&sh.tile[0][swz(r1, o1)] = cvt8(a10, a11);
      if (BTR) {
#pragma unroll
        for (int p = 0; p < 2; ++p) {
          short8 h;
#pragma unroll
          for (int e = 0; e < 8; ++e) h[e] = (short)f2b(btv[p][e]);
          *(short8*)&sh.tile[1][swz(lane + p * 64, wv * 8)] = h;
        }
      } else {
        *(short8*)&sh.tile[1][swz(r0, o0)] = cvt8(bb[0], bb[1]);
        *(short8*)&sh.tile[1][swz(r1, o1)] = cvt8(bb[2], bb[3]);
      }
    }
    __syncthreads();

    short8 afh[4], bfh[4];
#pragma unroll
    for (int i = 0; i < 4; ++i)
      afh[i] = *(const short8*)&sh.tile[0][swz(wm * 64 + i * 16 + fr, kg * 8)];
#pragma unroll
    for (int j = 0; j < 4; ++j)
      bfh[j] = *(const short8*)&sh.tile[1][swz(wn * 64 + j * 16 + fr, kg * 8)];

    if (SPLIT) {
      short8 afl[4], bfl[4];
#pragma unroll
      for (int i = 0; i < 4; ++i)
        afl[i] = *(const short8*)&sh.tile[2][swz(wm * 64 + i * 16 + fr, kg * 8)];
#pragma unroll
      for (int j = 0; j < 4; ++j)
        bfl[j] = *(const short8*)&sh.tile[3][swz(wn * 64 + j * 16 + fr, kg * 8)];
#pragma unroll
      for (int i = 0; i < 4; ++i)
#pragma unroll
        for (int j = 0; j < 4; ++j) {
          acc[i][j] = __builtin_amdgcn_mfma_f32_16x16x32_bf16(afh[i], bfh[j], acc[i][j], 0, 0, 0);
          acc[i][j] = __builtin_amdgcn_mfma_f32_16x16x32_bf16(afh[i], bfl[j], acc[i][j], 0, 0, 0);
          acc[i][j] = __builtin_amdgcn_mfma_f32_16x16x32_bf16(afl[i], bfh[j], acc[i][j], 0, 0, 0);
        }
    } else {
#pragma unroll
      for (int i = 0; i < 4; ++i)
#pragma unroll
        for (int j = 0; j < 4; ++j)
          acc[i][j] = __builtin_amdgcn_mfma_f32_16x16x32_bf16(afh[i], bfh[j], acc[i][j], 0, 0, 0);
    }
  }

  if (DO_MASK) {
    __syncthreads();
    const int* mb = mask + (long)batch * sMask;
#pragma unroll
    for (int it = 0; it < 16; ++it) {
      int ql = it * 8 + (t >> 5);
      int kl = (t & 31) * 4;
      int4 mv = *(const int4*)(mb + (long)(n0 + ql) * mask_ld + (m0 + kl));
      sh.m[kl + 0][ql] = (unsigned char)(mv.x != 0);
      sh.m[kl + 1][ql] = (unsigned char)(mv.y != 0);
      sh.m[kl + 2][ql] = (unsigned char)(mv.z != 0);
      sh.m[kl + 3][ql] = (unsigned char)(mv.w != 0);
    }
    __syncthreads();
  }

  float bv[4];
  if (ADD_BIAS) {
#pragma unroll
    for (int j = 0; j < 4; ++j)
      bv[j] = bias[n0 + wn * 64 + j * 16 + fr];
  }

#pragma unroll
  for (int i = 0; i < 4; ++i) {
#pragma unroll
    for (int r = 0; r < 4; ++r) {
      int row = wm * 64 + i * 16 + (lane >> 4) * 4 + r;
      long gro = (long)batch * sC + (long)(m0 + row) * ldc + n0;
#pragma unroll
      for (int j = 0; j < 4; ++j) {
        int col = wn * 64 + j * 16 + fr;
        float v = acc[i][j][r];
        if (ADD_BIAS) v += bv[j];
        if (DO_MASK && sh.m[row][col]) v = -1e30f;
        C[gro + col] = v;
      }
    }
  }
}

// elementwise fp32 -> bf16 hi/lo split (len multiple of 2048)
__global__ __launch_bounds__(256)
void conv_split(const float* __restrict__ in, u16* __restrict__ hi, u16* __restrict__ lo)
{
  long i = ((long)blockIdx.x * 256 + threadIdx.x) * 8;
  float4 v0 = *(const float4*)(in + i);
  float4 v1 = *(const float4*)(in + i + 4);
  short8 h, l;
  cvt8_split(v0, v1, &h, &l);
  *(short8*)(hi + i) = h;
  *(short8*)(lo + i) = l;
}

// value [B][S1][H] fp32 -> vT [B][H][S1] bf16, 64x64 LDS tiles
__global__ __launch_bounds__(256)
void transpose_conv(const float* __restrict__ v, u16* __restrict__ vt)
{
  __shared__ u16 tl[64][66];
  const int b  = blockIdx.z;
  const int s0 = blockIdx.x * 64, h0 = blockIdx.y * 64;
  const int tr = threadIdx.x >> 4;
  const int tc = (threadIdx.x & 15) * 4;
  const float* vb = v + ((long)b * S1_ + s0) * H_ + h0;
#pragma unroll
  for (int q = 0; q < 4; ++q) {
    int r = tr + q * 16;
    float4 x = *(const float4*)(vb + (long)r * H_ + tc);
    tl[r][tc + 0] = f2b(x.x); tl[r][tc + 1] = f2b(x.y);
    tl[r][tc + 2] = f2b(x.z); tl[r][tc + 3] = f2b(x.w);
  }
  __syncthreads();
  u16* ob = vt + ((long)b * H_ + h0) * S1_ + s0;
#pragma unroll
  for (int q = 0; q < 4; ++q) {
    int hr = tr + q * 16;
    unsigned int w0 = (unsigned int)tl[tc + 0][hr] | ((unsigned int)tl[tc + 1][hr] << 16);
    unsigned int w1 = (unsigned int)tl[tc + 2][hr] | ((unsigned int)tl[tc + 3][hr] << 16);
    uint2 w = {w0, w1};
    *(uint2*)(ob + (long)hr * S1_ + tc) = w;
  }
}

// one block per row: in-place fp32 softmax over S1; optional bf16 copy
__global__ __launch_bounds__(256)
void softmax_rows(float* __restrict__ scores, u16* __restrict__ wbf)
{
  const long row = blockIdx.x;
  float* p = scores + row * (long)S1_;
  const int t = threadIdx.x;
  const int lane = t & 63, wv = t >> 6;

  float4 v0 = *(const float4*)(p + t * 8);
  float4 v1 = *(const float4*)(p + t * 8 + 4);
  float x[8] = {v0.x, v0.y, v0.z, v0.w, v1.x, v1.y, v1.z, v1.w};

  float m = x[0];
#pragma unroll
  for (int q = 1; q < 8; ++q) m = fmaxf(m, x[q]);
#pragma unroll
  for (int o = 32; o; o >>= 1) m = fmaxf(m, __shfl_xor(m, o));
  __shared__ float rb[4], sb[4];
  if (lane == 0) rb[wv] = m;
  __syncthreads();
  m = fmaxf(fmaxf(rb[0], rb[1]), fmaxf(rb[2], rb[3]));

  float e[8]; float s = 0.f;
#pragma unroll
  for (int q = 0; q < 8; ++q) { e[q] = __expf(x[q] - m); s += e[q]; }
#pragma unroll
  for (int o = 32; o; o >>= 1) s += __shfl_xor(s, o);
  if (lane == 0) sb[wv] = s;
  __syncthreads();
  s = sb[0] + sb[1] + sb[2] + sb[3];
  float inv = 1.f / s;

  float w[8];
#pragma unroll
  for (int q = 0; q < 8; ++q) w[q] = e[q] * inv;
  float4 o0 = {w[0], w[1], w[2], w[3]};
  float4 o1 = {w[4], w[5], w[6], w[7]};
  *(float4*)(p + t * 8)     = o0;
  *(float4*)(p + t * 8 + 4) = o1;

  if (wbf != nullptr) {
    short8 hb;
#pragma unroll
    for (int q = 0; q < 8; ++q) hb[q] = (short)f2b(w[q]);
    *(short8*)(wbf + row * (long)S1_ + t * 8) = hb;
  }
}

extern "C" void kernel_launch(void* const* d_in, const int* in_sizes, int n_in,
                              void* d_out, int out_size, void* d_ws, size_t ws_size,
                              hipStream_t stream)
{
  const float* value = (const float*)d_in[0];
  const float* key   = (const float*)d_in[1];
  const float* query = (const float*)d_in[2];
  const int*   mask  = (const int*)d_in[3];
  const float* W     = (const float*)d_in[4];
  const float* bias  = (const float*)d_in[5];

  float* ctx = (float*)d_out;                       // [B,S2,H] fp32 (final context)
  float* wts = ctx + (size_t)B_ * S2_ * H_;         // [B,S2,S1] fp32 (scores -> weights)

  dim3 blk(256);
  const size_t MB = 1024ull * 1024ull;

  if (ws_size >= 132 * MB && d_ws != nullptr) {
    // ---------------- PATH A: pre-converted bf16 operands ----------------
    u16* pjhi = (u16*)ctx;                            // 32MB (q_proj hi, dies at K5)
    u16* pjlo = (u16*)ctx + (size_t)B_ * S1_ * H_;    // 32MB

    char* ws = (char*)d_ws;
    u16* khi = (u16*)(ws);
    u16* klo = (u16*)(ws + 32 * MB);
    u16* wbf = (u16*)(ws);                 // 64MB, after K2
    u16* qhi = (u16*)(ws + 64 * MB);
    u16* qlo = (u16*)(ws + 96 * MB);
    u16* vT  = (u16*)(ws + 64 * MB);       // 32MB, after K1
    u16* whi = (u16*)(ws + 128 * MB);
    u16* wlo = (u16*)(ws + 130 * MB);

    conv_split<<<dim3((B_ * S1_ * H_) / 2048), blk, 0, stream>>>(query, qhi, qlo);
    conv_split<<<dim3((B_ * S2_ * H_) / 2048), blk, 0, stream>>>(key, khi, klo);
    conv_split<<<dim3((H_ * H_) / 2048), blk, 0, stream>>>(W, whi, wlo);

    // K1: q_proj = query @ W^T + b -> bf16 hi/lo planes in ctx region
    gemm_bf<true, false, true, true><<<dim3((B_ * S1_) / 128, H_ / 128, 1), blk, 0, stream>>>(
        qhi, qlo, 0, H_, whi, wlo, 0, H_, bias,
        nullptr, 0, 0, nullptr, pjhi, pjlo, 0, H_, H_);

    // P1: value -> vT bf16 (into dead qhi/qlo region; after K1 in stream order)
    transpose_conv<<<dim3(S1_ / 64, H_ / 64, B_), blk, 0, stream>>>(value, vT);

    // K2: scores[b,s2,s1] = key @ q_proj^T, masked -> fp32 in wts
    gemm_bf<false, true, true, false><<<dim3(S2_ / 128, S1_ / 128, B_), blk, 0, stream>>>(
        khi, klo, (long)S2_ * H_, H_, pjhi, pjlo, (long)S1_ * H_, H_, nullptr,
        mask, (long)S1_ * S2_, S2_, wts, nullptr, nullptr, (long)S2_ * S1_, S1_, H_);

    // K3: softmax in-place + bf16 copy into dead khi/klo region
    softmax_rows<<<dim3(B_ * S2_), blk, 0, stream>>>(wts, wbf);

    // K5: context = weights_bf16 @ value^T_bf16
    gemm_bf<false, false, false, false><<<dim3(S2_ / 128, H_ / 128, B_), blk, 0, stream>>>(
        wbf, nullptr, (long)S2_ * S1_, S1_, vT, nullptr, (long)H_ * S1_, S1_, nullptr,
        nullptr, 0, 0, ctx, nullptr, nullptr, (long)S2_ * H_, H_, S1_);
  } else {
    // ---------------- PATH B: zero-workspace fallback (971us, verified) ----
    float* qproj = ctx;   // [B,S1,H] fp32 == ctx region exactly

    gemm_k<true, false, true, false><<<dim3((B_ * S1_) / 128, H_ / 128, 1), blk, 0, stream>>>(
        query, 0, W, 0, H_, bias, nullptr, 0, 0, qproj, 0, H_, H_);

    gemm_k<false, true, true, false><<<dim3(S2_ / 128, S1_ / 128, B_), blk, 0, stream>>>(
        key, (long)S2_ * H_, qproj, (long)S1_ * H_, H_, nullptr,
        mask, (long)S1_ * S2_, S2_, wts, (long)S2_ * S1_, S1_, H_);

    softmax_rows<<<dim3(B_ * S2_), blk, 0, stream>>>(wts, nullptr);

    gemm_k<false, false, false, true><<<dim3(S2_ / 128, H_ / 128, B_), blk, 0, stream>>>(
        wts, (long)S2_ * S1_, value, (long)S1_ * H_, H_, nullptr,
        nullptr, 0, 0, ctx, (long)S2_ * H_, H_, S1_);
  }
}